// Round 12
// baseline (410.710 us; speedup 1.0000x reference)
//
#include <hip/hip_runtime.h>
#include <hip/hip_bf16.h>

#define BB   4
#define LL   8192
#define HH   256
#define NN   64
#define NSEG 128
#define LSEG 64
#define YCS  258   // yc LDS row stride (f32): 256+2 -> carry-store bank-conflict-free

typedef __attribute__((ext_vector_type(8))) short  short8;
typedef __attribute__((ext_vector_type(4))) float  float4v;
typedef __attribute__((ext_vector_type(4))) int    int4v;

// ws layout (bytes):
//       0 : lam[128]     f32   lambda (re,im)
//     512 : lam64[128]   f32   lambda^64
//    1024 : flags[8]     i32
//    1088 : Df[256]      f32
//    2112 : CBt[128*256] f32   [n2][h]
//  133184 : Ktab[64*256] f32   [j][h]   K[h,j]=Re(sum_n CB lam^j)
//  198720 : VreT[64*64]  bf16  [tau][n] Re(lam^{tau+1})        (MFMA A-layout)
//  206912 : VimnT[64*64] bf16  [tau][n] -Im(lam^{tau+1})
//  215104 : PsegRe[64*64]f32   [l][n]   Re(lam^{63-l}) exact
//  231744 : PsegIm[64*64]f32   [l][n]   Im(lam^{63-l}) exact
//  248128 : PreH[64*64]  bf16  [n][l]   hi(Re lam^{63-l})      (MFMA A-layout)
//  256320 : PreL[64*64]  bf16  [n][l]   lo(Re lam^{63-l})
//  264512 : PimH[64*64]  bf16  [n][l]   hi(Im lam^{63-l})
//  272704 : PimL[64*64]  bf16  [n][l]   lo(Im lam^{63-l})
//  294912 : Apack u32 33 MB    [b*4+hg][s][n][64 h] {bf16 im|re} A->(scan)->U
//
// R19: R18 base + ONE change: cc's conv phase rebalanced across waves.
// Wave u now owns strided rows r=u+4t (t=0..15) instead of quadrant
// u*16..u*16+15, killing the 4x static work imbalance (worst wave ~904
// fmaf -> ~560). Source rows are walked DESCENDING so each output row
// receives its taps in ascending j with the D-term first — the identical
// FLOP sequence as before => bitwise-identical output.

__device__ __forceinline__ float ldF(const void* p, size_t i, int isbf) {
    return isbf ? __bfloat162float(((const __hip_bfloat16*)p)[i])
                : ((const float*)p)[i];
}

__device__ __forceinline__ int sniff1(const void* p) {
    const unsigned int* d = (const unsigned int*)p;
    int nbf = 0, nrand = 0;
    #pragma unroll
    for (int i = 0; i < 32; ++i) {
        unsigned int lo = d[i] & 0xFFFFu;
        unsigned int e  = (lo >> 7) & 0xFFu;
        if (lo == 0u) { /* neutral */ }
        else if (e >= 90u && e <= 140u) nbf++;
        else nrand++;
    }
    return (nrand == 0 && nbf >= 8) ? 1 : 0;
}

__device__ __forceinline__ unsigned int packbf(float re, float im) {
    __hip_bfloat16 hr = __float2bfloat16(re);
    __hip_bfloat16 hi = __float2bfloat16(im);
    return ((unsigned int)*(unsigned short*)&hi << 16)
         |  (unsigned int)*(unsigned short*)&hr;
}
__device__ __forceinline__ float unpkre(unsigned int u) {
    unsigned short s = (unsigned short)(u & 0xFFFFu);
    return __bfloat162float(*(__hip_bfloat16*)&s);
}
__device__ __forceinline__ float unpkim(unsigned int u) {
    unsigned short s = (unsigned short)(u >> 16);
    return __bfloat162float(*(__hip_bfloat16*)&s);
}

__global__ __launch_bounds__(256) void k_setup(
    const void* x, const void* nu_log, const void* theta_log,
    const void* B_re, const void* B_im,
    const void* C_re, const void* C_im,
    const void* D, int* flags,
    float* lam, float* lam64, float* Df, float* CBt,
    float* PsegRe, float* PsegIm)
{
    __shared__ int sf[8];
    {
        int tt = threadIdx.x;
        if (tt < 8) {
            const void* ps[8] = {x, nu_log, theta_log, B_re, B_im,
                                 C_re, C_im, D};
            sf[tt] = sniff1(ps[tt]);
        }
        __syncthreads();
        if (blockIdx.x == 0 && tt < 8) flags[tt] = sf[tt];
    }
    int t = blockIdx.x * 256 + threadIdx.x;
    if (t < NN) {
        float nu = expf(ldF(nu_log, t, sf[1]));
        float th = expf(ldF(theta_log, t, sf[2]));
        float a  = expf(-nu);
        lam[2*t]   = a * cosf(th);
        lam[2*t+1] = a * sinf(th);
        float a64 = expf(-64.0f * nu);
        float ph  = 64.0f * th;
        lam64[2*t]   = a64 * cosf(ph);
        lam64[2*t+1] = a64 * sinf(ph);
    }
    if (t < HH) Df[t] = ldF(D, t, sf[7]);
    if (t < HH * NN) {
        int h = t >> 6, n = t & 63;
        float bre = ldF(B_re, h*NN+n, sf[3]);
        float bim = ldF(B_im, h*NN+n, sf[4]);
        float cre = ldF(C_re, h*NN+n, sf[5]);
        float cim = ldF(C_im, h*NN+n, sf[6]);
        CBt[(n*2+0)*HH + h] = cre*bre - cim*bim;
        CBt[(n*2+1)*HH + h] = cre*bim + cim*bre;
    }
    if (t < 64 * 64) {
        int l = t >> 6, n = t & 63;
        float nu = expf(ldF(nu_log, n, sf[1]));
        float th = expf(ldF(theta_log, n, sf[2]));
        float fp = (float)(63 - l);
        float ar = expf(-fp * nu);
        PsegRe[t] = ar * cosf(fp * th);
        PsegIm[t] = ar * sinf(fp * th);
    }
}

// Ktab from exact f32 powers; V tables (bf16, [tau][n]) for the carry GEMM;
// split-bf16 P tables ([n][l]) for the segsum GEMM.
// Pseg[l][n] = lam^{63-l}  ->  power j lives at Pseg[63-j]; power 64 = lam64.
__global__ __launch_bounds__(256) void k_ktab(
    const float* __restrict__ CBt, const float* __restrict__ PsegRe,
    const float* __restrict__ PsegIm, const float* __restrict__ lam64,
    float* __restrict__ Ktab,
    short* __restrict__ VreT, short* __restrict__ VimnT,
    short* __restrict__ PreH, short* __restrict__ PreL,
    short* __restrict__ PimH, short* __restrict__ PimL)
{
    int t = blockIdx.x * 256 + threadIdx.x;    // 16384
    int h = t >> 6, j = t & 63;
    float acc = 0.f;
    for (int n = 0; n < NN; ++n)
        acc += CBt[(2*n)*HH + h]   * PsegRe[(63-j)*64 + n]
             - CBt[(2*n+1)*HH + h] * PsegIm[(63-j)*64 + n];
    Ktab[j*HH + h] = acc;
    if (t < 64*64) {
        int tau = t >> 6, n = t & 63;
        float vr, vi;
        if (tau < 63) {
            vr =  PsegRe[(62-tau)*64 + n];   // power tau+1
            vi = -PsegIm[(62-tau)*64 + n];
        } else {
            vr =  lam64[2*n];                // power 64, exact
            vi = -lam64[2*n+1];
        }
        __hip_bfloat16 br = __float2bfloat16(vr);
        __hip_bfloat16 bi = __float2bfloat16(vi);
        VreT[tau*64 + n]  = *(short*)&br;
        VimnT[tau*64 + n] = *(short*)&bi;

        // split P tables, A-layout [n][l]: t = n*64 + l
        int n2 = t >> 6, l2 = t & 63;
        float pr = PsegRe[l2*64 + n2];
        float pi = PsegIm[l2*64 + n2];
        __hip_bfloat16 prh = __float2bfloat16(pr);
        __hip_bfloat16 prl = __float2bfloat16(pr - __bfloat162float(prh));
        __hip_bfloat16 pih = __float2bfloat16(pi);
        __hip_bfloat16 pil = __float2bfloat16(pi - __bfloat162float(pih));
        PreH[t] = *(short*)&prh;
        PreL[t] = *(short*)&prl;
        PimH[t] = *(short*)&pih;
        PimL[t] = *(short*)&pil;
    }
}

// ---------- Phase A: A[n][h] = sum_l Pseg[l][n] x[l][h]  (MFMA GEMM) -------
// Per block one (b,s) tile, 4 waves (wave = hg), nt-loop inside.
// x tile staged through LDS as packed {lo:hi} split-bf16 u32 [l][h] (64KB).
// A-frag: a[j] = PT[n = mt*16+l15][l = ks*32+q*8+j]   (row-major [n][l])
// B-frag: b[j] = Xsh[l = ks*32+q*8+j][h = hg*64+nt*16+l15]
// D:      row n = mt*16+q*4+r, col h_local = nt*16+l15
template<bool ISBF>
__device__ __forceinline__ void segsum_body(
    const void* __restrict__ x, size_t sb, unsigned int* __restrict__ xsh,
    const short* __restrict__ PreH, const short* __restrict__ PreL,
    const short* __restrict__ PimH, const short* __restrict__ PimL,
    unsigned int* __restrict__ Apack, size_t abase, int w, int q, int l15)
{
    int t = threadIdx.x;
    // ---- stage: coalesced global loads -> split-bf16 packed u32 in LDS ----
    if (ISBF) {
        const short8* xp = (const short8*)((const short*)x + sb);
        #pragma unroll
        for (int i = 0; i < 8; ++i) {
            short8 v = xp[i*256 + t];
            int e = (i*256 + t) * 8;
            #pragma unroll
            for (int k = 0; k < 8; ++k)
                xsh[e + k] = (unsigned int)(unsigned short)v[k];   // hi=x, lo=0
        }
    } else {
        const float4v* xp = (const float4v*)((const float*)x + sb);
        #pragma unroll
        for (int i = 0; i < 16; ++i) {
            float4v v = xp[i*256 + t];
            int e = (i*256 + t) * 4;
            #pragma unroll
            for (int k = 0; k < 4; ++k) {
                float xf = v[k];
                __hip_bfloat16 hv = __float2bfloat16(xf);
                __hip_bfloat16 lv = __float2bfloat16(xf - __bfloat162float(hv));
                xsh[e + k] = ((unsigned int)*(unsigned short*)&lv << 16)
                           |  (unsigned int)*(unsigned short*)&hv;
            }
        }
    }
    __syncthreads();

    #pragma unroll
    for (int nt = 0; nt < 4; ++nt) {
        short8 xh[2], xl[2];
        #pragma unroll
        for (int ks = 0; ks < 2; ++ks)
            #pragma unroll
            for (int j = 0; j < 8; ++j) {
                unsigned int u = xsh[(ks*32 + q*8 + j)*256 + w*64 + nt*16 + l15];
                xh[ks][j] = (short)(u & 0xFFFFu);
                if (!ISBF) xl[ks][j] = (short)(u >> 16);
            }
        #pragma unroll
        for (int mt = 0; mt < 4; ++mt) {
            float4v ar = {0.f, 0.f, 0.f, 0.f};
            float4v ai = {0.f, 0.f, 0.f, 0.f};
            #pragma unroll
            for (int ks = 0; ks < 2; ++ks) {
                int off = (mt*16 + l15)*64 + ks*32 + q*8;
                short8 prh = *(const short8*)(PreH + off);
                short8 pih = *(const short8*)(PimH + off);
                short8 prl = *(const short8*)(PreL + off);
                short8 pil = *(const short8*)(PimL + off);
                ar = __builtin_amdgcn_mfma_f32_16x16x32_bf16(prh, xh[ks], ar, 0, 0, 0);
                ai = __builtin_amdgcn_mfma_f32_16x16x32_bf16(pih, xh[ks], ai, 0, 0, 0);
                ar = __builtin_amdgcn_mfma_f32_16x16x32_bf16(prl, xh[ks], ar, 0, 0, 0);
                ai = __builtin_amdgcn_mfma_f32_16x16x32_bf16(pil, xh[ks], ai, 0, 0, 0);
                if (!ISBF) {
                    ar = __builtin_amdgcn_mfma_f32_16x16x32_bf16(prh, xl[ks], ar, 0, 0, 0);
                    ai = __builtin_amdgcn_mfma_f32_16x16x32_bf16(pih, xl[ks], ai, 0, 0, 0);
                }
            }
            #pragma unroll
            for (int r = 0; r < 4; ++r) {
                int n = mt*16 + q*4 + r;
                Apack[abase + (size_t)n*64 + nt*16 + l15] = packbf(ar[r], ai[r]);
            }
        }
    }
}

__global__ __launch_bounds__(256) void k_segsum(
    const void* __restrict__ x,
    const short* __restrict__ PreH, const short* __restrict__ PreL,
    const short* __restrict__ PimH, const short* __restrict__ PimL,
    const int* __restrict__ flags, unsigned int* __restrict__ Apack)
{
    __shared__ unsigned int xsh[64 * 256];   // 64 KB packed {lo:hi} bf16
    int bk = blockIdx.x;                 // 512 = (b, s)
    int s  = bk & (NSEG - 1);
    int b  = bk >> 7;
    int w    = threadIdx.x >> 6;         // wave = hg
    int lane = threadIdx.x & 63;
    int q = lane >> 4, l15 = lane & 15;

    size_t sb    = ((size_t)(b*LL) + s*64) * HH;
    size_t abase = (((size_t)(b*4 + w) * NSEG + s) * NN) * 64;

    if (flags[0]) segsum_body<true >(x, sb, xsh, PreH, PreL, PimH, PimL, Apack, abase, w, q, l15);
    else          segsum_body<false>(x, sb, xsh, PreH, PreL, PimH, PimL, Apack, abase, w, q, l15);
}

// ---------- Phase B: scan + U = CB*S_{s-1} epilogue (in place) ----------
// Software-pipelined: 4 blocks of 32 s-steps; 32-step compute (~640cy)
// fully covers the ~600cy global latency of the next batch's loads.
__global__ __launch_bounds__(256) void k_scan(
    const float* __restrict__ lam64, const float* __restrict__ CBt,
    unsigned int* __restrict__ Apack)
{
    int w    = blockIdx.x * 4 + (threadIdx.x >> 6);
    int lane = threadIdx.x & 63;
    int n    = w & 63;
    int hg   = (w >> 6) & 3;
    int b    = w >> 8;
    int h    = hg*64 + lane;

    float lre = lam64[2*n], lim = lam64[2*n+1];
    float cbre = CBt[(2*n)*HH + h], cbim = CBt[(2*n+1)*HH + h];
    float sre = 0.f, sim = 0.f;
    size_t base0 = (((size_t)(b*4 + hg) * NSEG) * NN + n) * 64 + lane;

    unsigned int curU[32], nxtU[32];
    #pragma unroll
    for (int k = 0; k < 32; ++k)
        curU[k] = Apack[base0 + (size_t)k * NN * 64];
    #pragma unroll
    for (int blk = 0; blk < 4; ++blk) {
        if (blk < 3) {
            #pragma unroll
            for (int k = 0; k < 32; ++k)
                nxtU[k] = Apack[base0 + (size_t)((blk+1)*32 + k) * NN * 64];
        }
        #pragma unroll
        for (int k = 0; k < 32; ++k) {
            size_t idx = base0 + (size_t)(blk*32 + k) * NN * 64;
            float are = unpkre(curU[k]);
            float aim = unpkim(curU[k]);
            float ure = cbre*sre - cbim*sim;
            float uim = cbre*sim + cbim*sre;
            Apack[idx] = packbf(ure, uim);
            float t2 = fmaf(lre, sre, fmaf(-lim, sim, are));
            sim = fmaf(lre, sim, fmaf(lim, sre, aim));
            sre = t2;
        }
        #pragma unroll
        for (int k = 0; k < 32; ++k) curU[k] = nxtU[k];
    }
}

// ---------- Phase C (fused): carry GEMM -> LDS, then conv on top ----------
// Conv rebalanced: wave UW owns strided rows r = UW + 4t (t=0..15), all
// waves ~equal fmaf. Source rows walked descending => per-row tap order is
// ascending j with D-term first: bitwise-identical to the quadrant form.
template<bool ISBF, int UW>
__device__ __forceinline__ void conv_b(
    const void* __restrict__ x, const float* __restrict__ Df,
    const float* __restrict__ Ktab, const float* __restrict__ yc,
    int b, int s, int h, float* __restrict__ y)
{
    int g0 = s*64;
    size_t sbase = ((size_t)b*LL + g0)*HH + h;
    float dh = Df[h];
    float kreg[61 + UW];                 // K[0 .. 60+UW]
    #pragma unroll
    for (int j = 0; j < 61 + UW; ++j) kreg[j] = Ktab[j*HH + h];
    float yv[16];
    #pragma unroll
    for (int t = 0; t < 16; ++t) yv[t] = yc[(UW + 4*t)*YCS + h];
    #pragma unroll
    for (int a = 60 + UW; a >= 0; --a) {     // a > 60+UW used by no row
        float xa;
        if (ISBF) xa = __bfloat162float(((const __hip_bfloat16*)x)[sbase + (size_t)a*HH]);
        else      xa = ((const float*)x)[sbase + (size_t)a*HH];
        #pragma unroll
        for (int t = 0; t < 16; ++t) {
            const int r = UW + 4*t;
            if (r == a) yv[t] = fmaf(dh, xa, yv[t]);        // D-term first
            if (r >= a) yv[t] = fmaf(kreg[r - a], xa, yv[t]); // then tap j=r-a
        }
    }
    #pragma unroll
    for (int t = 0; t < 16; ++t)
        y[sbase + (size_t)(UW + 4*t)*HH] = yv[t];
}

template<bool ISBF>
__device__ __forceinline__ void cc_body(
    const short* __restrict__ VreT, const short* __restrict__ VimnT,
    const unsigned int* __restrict__ Upack, const void* __restrict__ x,
    const float* __restrict__ Df, const float* __restrict__ Ktab,
    float* yc, int b, int s, float* __restrict__ y)
{
    int t = threadIdx.x;

    // ---- carry GEMM: wave (hg = w&3, nt = w>>2), output -> yc LDS ----
    int w = t >> 6, lane = t & 63;
    int hg = w & 3, nt = w >> 2;
    int q = lane >> 4, l15 = lane & 15;
    size_t ubase = (((size_t)(b*4 + hg) * NSEG + s) * NN) * 64;

    int l = nt*16 + l15;
    short8 bre[2], bim[2];
    #pragma unroll
    for (int ks = 0; ks < 2; ++ks)
        #pragma unroll
        for (int j = 0; j < 8; ++j) {
            int n = ks*32 + q*8 + j;
            unsigned int u = Upack[ubase + (size_t)n*64 + l];
            bre[ks][j] = (short)(u & 0xFFFFu);
            bim[ks][j] = (short)(u >> 16);
        }
    int h = hg*64 + l;
    #pragma unroll
    for (int mt = 0; mt < 4; ++mt) {
        float4v acc = {0.f, 0.f, 0.f, 0.f};
        #pragma unroll
        for (int ks = 0; ks < 2; ++ks) {
            int off = (mt*16 + l15)*64 + ks*32 + q*8;
            short8 afr = *(const short8*)(VreT + off);
            short8 afi = *(const short8*)(VimnT + off);
            acc = __builtin_amdgcn_mfma_f32_16x16x32_bf16(afr, bre[ks], acc, 0, 0, 0);
            acc = __builtin_amdgcn_mfma_f32_16x16x32_bf16(afi, bim[ks], acc, 0, 0, 0);
        }
        #pragma unroll
        for (int r = 0; r < 4; ++r) {
            int tau = mt*16 + q*4 + r;
            yc[tau*YCS + h] = acc[r];
        }
    }

    __syncthreads();

    // ---- conv phase: wave (u = w>>2 row-residue, hg = w&3) ----
    int u = w >> 2;
    int h2 = hg*64 + lane;
    switch (u) {
        case 0: conv_b<ISBF,0>(x, Df, Ktab, yc, b, s, h2, y); break;
        case 1: conv_b<ISBF,1>(x, Df, Ktab, yc, b, s, h2, y); break;
        case 2: conv_b<ISBF,2>(x, Df, Ktab, yc, b, s, h2, y); break;
        case 3: conv_b<ISBF,3>(x, Df, Ktab, yc, b, s, h2, y); break;
    }
}

__global__ __launch_bounds__(1024) void k_cc(
    const short* __restrict__ VreT, const short* __restrict__ VimnT,
    const unsigned int* __restrict__ Upack, const void* __restrict__ x,
    const float* __restrict__ Df, const float* __restrict__ Ktab,
    const int* __restrict__ flags, float* __restrict__ y)
{
    __shared__ float yc[64 * YCS];  // 66 KB carry output (padded stride)
    int bk = blockIdx.x;            // 512 = (b, s)
    int s  = bk & (NSEG - 1);
    int b  = bk >> 7;
    if (flags[0]) cc_body<true >(VreT, VimnT, Upack, x, Df, Ktab, yc, b, s, y);
    else          cc_body<false>(VreT, VimnT, Upack, x, Df, Ktab, yc, b, s, y);
}

extern "C" void kernel_launch(void* const* d_in, const int* in_sizes, int n_in,
                              void* d_out, int out_size, void* d_ws, size_t ws_size,
                              hipStream_t stream)
{
    const void* x  = d_in[0];
    const void* nu = d_in[1];
    const void* th = d_in[2];
    const void* Br = d_in[3];
    const void* Bi = d_in[4];
    const void* Cr = d_in[5];
    const void* Ci = d_in[6];
    const void* D  = d_in[7];

    char* ws = (char*)d_ws;
    float* lam    = (float*)(ws);
    float* lam64  = (float*)(ws + 512);
    int*   flags  = (int*)(ws + 1024);
    float* Df     = (float*)(ws + 1088);
    float* CBt    = (float*)(ws + 2112);
    float* Ktab   = (float*)(ws + 133184);
    short* VreT   = (short*)(ws + 198720);
    short* VimnT  = (short*)(ws + 206912);
    float* PsegRe = (float*)(ws + 215104);
    float* PsegIm = (float*)(ws + 231744);
    short* PreH   = (short*)(ws + 248128);
    short* PreL   = (short*)(ws + 256320);
    short* PimH   = (short*)(ws + 264512);
    short* PimL   = (short*)(ws + 272704);
    unsigned int* Apack = (unsigned int*)(ws + 294912);
    float* yout = (float*)d_out;

    k_setup<<<dim3(64), dim3(256), 0, stream>>>(x, nu, th, Br, Bi, Cr, Ci, D,
                                                flags, lam, lam64, Df, CBt,
                                                PsegRe, PsegIm);
    k_ktab<<<dim3(64), dim3(256), 0, stream>>>(CBt, PsegRe, PsegIm, lam64,
                                               Ktab, VreT, VimnT,
                                               PreH, PreL, PimH, PimL);
    k_segsum<<<dim3(512), dim3(256), 0, stream>>>(x, PreH, PreL, PimH, PimL,
                                                  flags, Apack);
    k_scan<<<dim3(256), dim3(256), 0, stream>>>(lam64, CBt, Apack);
    k_cc<<<dim3(512), dim3(1024), 0, stream>>>(VreT, VimnT, Apack,
                                               x, Df, Ktab, flags, yout);
}

// Round 13
// 175.047 us; speedup vs baseline: 2.3463x; 2.3463x over previous
//
#include <hip/hip_runtime.h>
#include <hip/hip_bf16.h>

#define BB   4
#define LL   8192
#define HH   256
#define NN   64
#define NSEG 128
#define LSEG 64
#define YCS  258   // yc LDS row stride (f32): 256+2 -> carry-store bank-conflict-free

typedef __attribute__((ext_vector_type(8))) short  short8;
typedef __attribute__((ext_vector_type(4))) float  float4v;
typedef __attribute__((ext_vector_type(4))) int    int4v;

// ws layout (bytes):
//       0 : lam[128]     f32   lambda (re,im)
//     512 : lam64[128]   f32   lambda^64
//    1024 : flags[8]     i32
//    1088 : Df[256]      f32
//    2112 : CBt[128*256] f32   [n2][h]
//  133184 : Ktab[64*256] f32   [j][h]   K[h,j]=Re(sum_n CB lam^j)
//  198720 : VreT[64*64]  bf16  [tau][n] Re(lam^{tau+1})        (MFMA A-layout)
//  206912 : VimnT[64*64] bf16  [tau][n] -Im(lam^{tau+1})
//  215104 : PsegRe[64*64]f32   [l][n]   Re(lam^{63-l}) exact
//  231744 : PsegIm[64*64]f32   [l][n]   Im(lam^{63-l}) exact
//  248128 : PreH[64*64]  bf16  [n][l]   hi(Re lam^{63-l})      (MFMA A-layout)
//  256320 : PreL[64*64]  bf16  [n][l]   lo(Re lam^{63-l})
//  264512 : PimH[64*64]  bf16  [n][l]   hi(Im lam^{63-l})
//  272704 : PimL[64*64]  bf16  [n][l]   lo(Im lam^{63-l})
//  294912 : Apack u32 33 MB    [b*4+hg][s][n][64 h] {bf16 im|re} A->(scan)->U
//
// R20: exact revert to R18 (best measured, 177.8us). R19's strided/
// sliding-window conv rebalance blew the register allocator (VGPR 44,
// kreg/yv demoted to scratch: FETCH 43->310MB, WRITE 33->160MB, k_cc
// 276us). The quadrant conv_u form with small regular unrolled tap loops
// is allocator-safe and is restored unchanged.

__device__ __forceinline__ float ldF(const void* p, size_t i, int isbf) {
    return isbf ? __bfloat162float(((const __hip_bfloat16*)p)[i])
                : ((const float*)p)[i];
}

__device__ __forceinline__ int sniff1(const void* p) {
    const unsigned int* d = (const unsigned int*)p;
    int nbf = 0, nrand = 0;
    #pragma unroll
    for (int i = 0; i < 32; ++i) {
        unsigned int lo = d[i] & 0xFFFFu;
        unsigned int e  = (lo >> 7) & 0xFFu;
        if (lo == 0u) { /* neutral */ }
        else if (e >= 90u && e <= 140u) nbf++;
        else nrand++;
    }
    return (nrand == 0 && nbf >= 8) ? 1 : 0;
}

__device__ __forceinline__ unsigned int packbf(float re, float im) {
    __hip_bfloat16 hr = __float2bfloat16(re);
    __hip_bfloat16 hi = __float2bfloat16(im);
    return ((unsigned int)*(unsigned short*)&hi << 16)
         |  (unsigned int)*(unsigned short*)&hr;
}
__device__ __forceinline__ float unpkre(unsigned int u) {
    unsigned short s = (unsigned short)(u & 0xFFFFu);
    return __bfloat162float(*(__hip_bfloat16*)&s);
}
__device__ __forceinline__ float unpkim(unsigned int u) {
    unsigned short s = (unsigned short)(u >> 16);
    return __bfloat162float(*(__hip_bfloat16*)&s);
}

__global__ __launch_bounds__(256) void k_setup(
    const void* x, const void* nu_log, const void* theta_log,
    const void* B_re, const void* B_im,
    const void* C_re, const void* C_im,
    const void* D, int* flags,
    float* lam, float* lam64, float* Df, float* CBt,
    float* PsegRe, float* PsegIm)
{
    __shared__ int sf[8];
    {
        int tt = threadIdx.x;
        if (tt < 8) {
            const void* ps[8] = {x, nu_log, theta_log, B_re, B_im,
                                 C_re, C_im, D};
            sf[tt] = sniff1(ps[tt]);
        }
        __syncthreads();
        if (blockIdx.x == 0 && tt < 8) flags[tt] = sf[tt];
    }
    int t = blockIdx.x * 256 + threadIdx.x;
    if (t < NN) {
        float nu = expf(ldF(nu_log, t, sf[1]));
        float th = expf(ldF(theta_log, t, sf[2]));
        float a  = expf(-nu);
        lam[2*t]   = a * cosf(th);
        lam[2*t+1] = a * sinf(th);
        float a64 = expf(-64.0f * nu);
        float ph  = 64.0f * th;
        lam64[2*t]   = a64 * cosf(ph);
        lam64[2*t+1] = a64 * sinf(ph);
    }
    if (t < HH) Df[t] = ldF(D, t, sf[7]);
    if (t < HH * NN) {
        int h = t >> 6, n = t & 63;
        float bre = ldF(B_re, h*NN+n, sf[3]);
        float bim = ldF(B_im, h*NN+n, sf[4]);
        float cre = ldF(C_re, h*NN+n, sf[5]);
        float cim = ldF(C_im, h*NN+n, sf[6]);
        CBt[(n*2+0)*HH + h] = cre*bre - cim*bim;
        CBt[(n*2+1)*HH + h] = cre*bim + cim*bre;
    }
    if (t < 64 * 64) {
        int l = t >> 6, n = t & 63;
        float nu = expf(ldF(nu_log, n, sf[1]));
        float th = expf(ldF(theta_log, n, sf[2]));
        float fp = (float)(63 - l);
        float ar = expf(-fp * nu);
        PsegRe[t] = ar * cosf(fp * th);
        PsegIm[t] = ar * sinf(fp * th);
    }
}

// Ktab from exact f32 powers; V tables (bf16, [tau][n]) for the carry GEMM;
// split-bf16 P tables ([n][l]) for the segsum GEMM.
// Pseg[l][n] = lam^{63-l}  ->  power j lives at Pseg[63-j]; power 64 = lam64.
__global__ __launch_bounds__(256) void k_ktab(
    const float* __restrict__ CBt, const float* __restrict__ PsegRe,
    const float* __restrict__ PsegIm, const float* __restrict__ lam64,
    float* __restrict__ Ktab,
    short* __restrict__ VreT, short* __restrict__ VimnT,
    short* __restrict__ PreH, short* __restrict__ PreL,
    short* __restrict__ PimH, short* __restrict__ PimL)
{
    int t = blockIdx.x * 256 + threadIdx.x;    // 16384
    int h = t >> 6, j = t & 63;
    float acc = 0.f;
    for (int n = 0; n < NN; ++n)
        acc += CBt[(2*n)*HH + h]   * PsegRe[(63-j)*64 + n]
             - CBt[(2*n+1)*HH + h] * PsegIm[(63-j)*64 + n];
    Ktab[j*HH + h] = acc;
    if (t < 64*64) {
        int tau = t >> 6, n = t & 63;
        float vr, vi;
        if (tau < 63) {
            vr =  PsegRe[(62-tau)*64 + n];   // power tau+1
            vi = -PsegIm[(62-tau)*64 + n];
        } else {
            vr =  lam64[2*n];                // power 64, exact
            vi = -lam64[2*n+1];
        }
        __hip_bfloat16 br = __float2bfloat16(vr);
        __hip_bfloat16 bi = __float2bfloat16(vi);
        VreT[tau*64 + n]  = *(short*)&br;
        VimnT[tau*64 + n] = *(short*)&bi;

        // split P tables, A-layout [n][l]: t = n*64 + l
        int n2 = t >> 6, l2 = t & 63;
        float pr = PsegRe[l2*64 + n2];
        float pi = PsegIm[l2*64 + n2];
        __hip_bfloat16 prh = __float2bfloat16(pr);
        __hip_bfloat16 prl = __float2bfloat16(pr - __bfloat162float(prh));
        __hip_bfloat16 pih = __float2bfloat16(pi);
        __hip_bfloat16 pil = __float2bfloat16(pi - __bfloat162float(pih));
        PreH[t] = *(short*)&prh;
        PreL[t] = *(short*)&prl;
        PimH[t] = *(short*)&pih;
        PimL[t] = *(short*)&pil;
    }
}

// ---------- Phase A: A[n][h] = sum_l Pseg[l][n] x[l][h]  (MFMA GEMM) -------
// Per block one (b,s) tile, 4 waves (wave = hg), nt-loop inside.
// x tile staged through LDS as packed {lo:hi} split-bf16 u32 [l][h] (64KB).
// A-frag: a[j] = PT[n = mt*16+l15][l = ks*32+q*8+j]   (row-major [n][l])
// B-frag: b[j] = Xsh[l = ks*32+q*8+j][h = hg*64+nt*16+l15]
// D:      row n = mt*16+q*4+r, col h_local = nt*16+l15
template<bool ISBF>
__device__ __forceinline__ void segsum_body(
    const void* __restrict__ x, size_t sb, unsigned int* __restrict__ xsh,
    const short* __restrict__ PreH, const short* __restrict__ PreL,
    const short* __restrict__ PimH, const short* __restrict__ PimL,
    unsigned int* __restrict__ Apack, size_t abase, int w, int q, int l15)
{
    int t = threadIdx.x;
    // ---- stage: coalesced global loads -> split-bf16 packed u32 in LDS ----
    if (ISBF) {
        const short8* xp = (const short8*)((const short*)x + sb);
        #pragma unroll
        for (int i = 0; i < 8; ++i) {
            short8 v = xp[i*256 + t];
            int e = (i*256 + t) * 8;
            #pragma unroll
            for (int k = 0; k < 8; ++k)
                xsh[e + k] = (unsigned int)(unsigned short)v[k];   // hi=x, lo=0
        }
    } else {
        const float4v* xp = (const float4v*)((const float*)x + sb);
        #pragma unroll
        for (int i = 0; i < 16; ++i) {
            float4v v = xp[i*256 + t];
            int e = (i*256 + t) * 4;
            #pragma unroll
            for (int k = 0; k < 4; ++k) {
                float xf = v[k];
                __hip_bfloat16 hv = __float2bfloat16(xf);
                __hip_bfloat16 lv = __float2bfloat16(xf - __bfloat162float(hv));
                xsh[e + k] = ((unsigned int)*(unsigned short*)&lv << 16)
                           |  (unsigned int)*(unsigned short*)&hv;
            }
        }
    }
    __syncthreads();

    #pragma unroll
    for (int nt = 0; nt < 4; ++nt) {
        short8 xh[2], xl[2];
        #pragma unroll
        for (int ks = 0; ks < 2; ++ks)
            #pragma unroll
            for (int j = 0; j < 8; ++j) {
                unsigned int u = xsh[(ks*32 + q*8 + j)*256 + w*64 + nt*16 + l15];
                xh[ks][j] = (short)(u & 0xFFFFu);
                if (!ISBF) xl[ks][j] = (short)(u >> 16);
            }
        #pragma unroll
        for (int mt = 0; mt < 4; ++mt) {
            float4v ar = {0.f, 0.f, 0.f, 0.f};
            float4v ai = {0.f, 0.f, 0.f, 0.f};
            #pragma unroll
            for (int ks = 0; ks < 2; ++ks) {
                int off = (mt*16 + l15)*64 + ks*32 + q*8;
                short8 prh = *(const short8*)(PreH + off);
                short8 pih = *(const short8*)(PimH + off);
                short8 prl = *(const short8*)(PreL + off);
                short8 pil = *(const short8*)(PimL + off);
                ar = __builtin_amdgcn_mfma_f32_16x16x32_bf16(prh, xh[ks], ar, 0, 0, 0);
                ai = __builtin_amdgcn_mfma_f32_16x16x32_bf16(pih, xh[ks], ai, 0, 0, 0);
                ar = __builtin_amdgcn_mfma_f32_16x16x32_bf16(prl, xh[ks], ar, 0, 0, 0);
                ai = __builtin_amdgcn_mfma_f32_16x16x32_bf16(pil, xh[ks], ai, 0, 0, 0);
                if (!ISBF) {
                    ar = __builtin_amdgcn_mfma_f32_16x16x32_bf16(prh, xl[ks], ar, 0, 0, 0);
                    ai = __builtin_amdgcn_mfma_f32_16x16x32_bf16(pih, xl[ks], ai, 0, 0, 0);
                }
            }
            #pragma unroll
            for (int r = 0; r < 4; ++r) {
                int n = mt*16 + q*4 + r;
                Apack[abase + (size_t)n*64 + nt*16 + l15] = packbf(ar[r], ai[r]);
            }
        }
    }
}

__global__ __launch_bounds__(256) void k_segsum(
    const void* __restrict__ x,
    const short* __restrict__ PreH, const short* __restrict__ PreL,
    const short* __restrict__ PimH, const short* __restrict__ PimL,
    const int* __restrict__ flags, unsigned int* __restrict__ Apack)
{
    __shared__ unsigned int xsh[64 * 256];   // 64 KB packed {lo:hi} bf16
    int bk = blockIdx.x;                 // 512 = (b, s)
    int s  = bk & (NSEG - 1);
    int b  = bk >> 7;
    int w    = threadIdx.x >> 6;         // wave = hg
    int lane = threadIdx.x & 63;
    int q = lane >> 4, l15 = lane & 15;

    size_t sb    = ((size_t)(b*LL) + s*64) * HH;
    size_t abase = (((size_t)(b*4 + w) * NSEG + s) * NN) * 64;

    if (flags[0]) segsum_body<true >(x, sb, xsh, PreH, PreL, PimH, PimL, Apack, abase, w, q, l15);
    else          segsum_body<false>(x, sb, xsh, PreH, PreL, PimH, PimL, Apack, abase, w, q, l15);
}

// ---------- Phase B: scan + U = CB*S_{s-1} epilogue (in place) ----------
// Software-pipelined: 4 blocks of 32 s-steps; 32-step compute (~640cy)
// fully covers the ~600cy global latency of the next batch's loads.
__global__ __launch_bounds__(256) void k_scan(
    const float* __restrict__ lam64, const float* __restrict__ CBt,
    unsigned int* __restrict__ Apack)
{
    int w    = blockIdx.x * 4 + (threadIdx.x >> 6);
    int lane = threadIdx.x & 63;
    int n    = w & 63;
    int hg   = (w >> 6) & 3;
    int b    = w >> 8;
    int h    = hg*64 + lane;

    float lre = lam64[2*n], lim = lam64[2*n+1];
    float cbre = CBt[(2*n)*HH + h], cbim = CBt[(2*n+1)*HH + h];
    float sre = 0.f, sim = 0.f;
    size_t base0 = (((size_t)(b*4 + hg) * NSEG) * NN + n) * 64 + lane;

    unsigned int curU[32], nxtU[32];
    #pragma unroll
    for (int k = 0; k < 32; ++k)
        curU[k] = Apack[base0 + (size_t)k * NN * 64];
    #pragma unroll
    for (int blk = 0; blk < 4; ++blk) {
        if (blk < 3) {
            #pragma unroll
            for (int k = 0; k < 32; ++k)
                nxtU[k] = Apack[base0 + (size_t)((blk+1)*32 + k) * NN * 64];
        }
        #pragma unroll
        for (int k = 0; k < 32; ++k) {
            size_t idx = base0 + (size_t)(blk*32 + k) * NN * 64;
            float are = unpkre(curU[k]);
            float aim = unpkim(curU[k]);
            float ure = cbre*sre - cbim*sim;
            float uim = cbre*sim + cbim*sre;
            Apack[idx] = packbf(ure, uim);
            float t2 = fmaf(lre, sre, fmaf(-lim, sim, are));
            sim = fmaf(lre, sim, fmaf(lim, sre, aim));
            sre = t2;
        }
        #pragma unroll
        for (int k = 0; k < 32; ++k) curU[k] = nxtU[k];
    }
}

// ---------- Phase C (fused): carry GEMM -> LDS, then conv on top ----------
// xm taps read the L1-hot x tile from global (no xs staging; fp32-exact).
template<bool ISBF, int U>
__device__ __forceinline__ void conv_u(
    const void* __restrict__ x, const float* __restrict__ Df,
    const float* __restrict__ Ktab, const float* __restrict__ yc,
    int b, int s, int h, float* __restrict__ y)
{
    int g0 = s*64 + U*16;
    size_t rbase = ((size_t)b*LL + g0)*HH + h;
    float xv[16], yv[16];
    float dh = Df[h];
    #pragma unroll
    for (int t = 0; t < 16; ++t) {
        float xl;
        if (ISBF) xl = __bfloat162float(((const __hip_bfloat16*)x)[rbase + (size_t)t*HH]);
        else      xl = ((const float*)x)[rbase + (size_t)t*HH];
        xv[t] = xl;
        yv[t] = fmaf(dh, xl, yc[(U*16 + t)*YCS + h]);   // carry from LDS
    }
    float kreg[16*U + 16];
    #pragma unroll
    for (int j = 0; j < 16*U + 16; ++j) kreg[j] = Ktab[j*HH + h];
    // taps j=0..15 vs in-register xv (j<=t)
    #pragma unroll
    for (int j = 0; j < 16; ++j)
        #pragma unroll
        for (int t = j; t < 16; ++t) yv[t] = fmaf(kreg[j], xv[t-j], yv[t]);
    // taps j=t+1..16U+t vs older rows (global, L1-hot)
    #pragma unroll
    for (int m = 0; m < 16*U; ++m) {
        float xm;
        size_t ra = ((size_t)b*LL + (g0 - 1 - m))*HH + h;
        if (ISBF) xm = __bfloat162float(((const __hip_bfloat16*)x)[ra]);
        else      xm = ((const float*)x)[ra];
        #pragma unroll
        for (int t = 0; t < 16; ++t) yv[t] = fmaf(kreg[t+1+m], xm, yv[t]);
    }
    #pragma unroll
    for (int t = 0; t < 16; ++t) y[rbase + (size_t)t*HH] = yv[t];
}

template<bool ISBF>
__device__ __forceinline__ void cc_body(
    const short* __restrict__ VreT, const short* __restrict__ VimnT,
    const unsigned int* __restrict__ Upack, const void* __restrict__ x,
    const float* __restrict__ Df, const float* __restrict__ Ktab,
    float* yc, int b, int s, float* __restrict__ y)
{
    int t = threadIdx.x;

    // ---- carry GEMM: wave (hg = w&3, nt = w>>2), output -> yc LDS ----
    int w = t >> 6, lane = t & 63;
    int hg = w & 3, nt = w >> 2;
    int q = lane >> 4, l15 = lane & 15;
    size_t ubase = (((size_t)(b*4 + hg) * NSEG + s) * NN) * 64;

    int l = nt*16 + l15;
    short8 bre[2], bim[2];
    #pragma unroll
    for (int ks = 0; ks < 2; ++ks)
        #pragma unroll
        for (int j = 0; j < 8; ++j) {
            int n = ks*32 + q*8 + j;
            unsigned int u = Upack[ubase + (size_t)n*64 + l];
            bre[ks][j] = (short)(u & 0xFFFFu);
            bim[ks][j] = (short)(u >> 16);
        }
    int h = hg*64 + l;
    #pragma unroll
    for (int mt = 0; mt < 4; ++mt) {
        float4v acc = {0.f, 0.f, 0.f, 0.f};
        #pragma unroll
        for (int ks = 0; ks < 2; ++ks) {
            int off = (mt*16 + l15)*64 + ks*32 + q*8;
            short8 afr = *(const short8*)(VreT + off);
            short8 afi = *(const short8*)(VimnT + off);
            acc = __builtin_amdgcn_mfma_f32_16x16x32_bf16(afr, bre[ks], acc, 0, 0, 0);
            acc = __builtin_amdgcn_mfma_f32_16x16x32_bf16(afi, bim[ks], acc, 0, 0, 0);
        }
        #pragma unroll
        for (int r = 0; r < 4; ++r) {
            int tau = mt*16 + q*4 + r;
            yc[tau*YCS + h] = acc[r];
        }
    }

    __syncthreads();

    // ---- conv phase: wave (u = w>>2, hg = w&3) ----
    int u = w >> 2;
    int h2 = hg*64 + lane;
    switch (u) {
        case 0: conv_u<ISBF,0>(x, Df, Ktab, yc, b, s, h2, y); break;
        case 1: conv_u<ISBF,1>(x, Df, Ktab, yc, b, s, h2, y); break;
        case 2: conv_u<ISBF,2>(x, Df, Ktab, yc, b, s, h2, y); break;
        case 3: conv_u<ISBF,3>(x, Df, Ktab, yc, b, s, h2, y); break;
    }
}

__global__ __launch_bounds__(1024) void k_cc(
    const short* __restrict__ VreT, const short* __restrict__ VimnT,
    const unsigned int* __restrict__ Upack, const void* __restrict__ x,
    const float* __restrict__ Df, const float* __restrict__ Ktab,
    const int* __restrict__ flags, float* __restrict__ y)
{
    __shared__ float yc[64 * YCS];  // 66 KB carry output (padded stride)
    int bk = blockIdx.x;            // 512 = (b, s)
    int s  = bk & (NSEG - 1);
    int b  = bk >> 7;
    if (flags[0]) cc_body<true >(VreT, VimnT, Upack, x, Df, Ktab, yc, b, s, y);
    else          cc_body<false>(VreT, VimnT, Upack, x, Df, Ktab, yc, b, s, y);
}

extern "C" void kernel_launch(void* const* d_in, const int* in_sizes, int n_in,
                              void* d_out, int out_size, void* d_ws, size_t ws_size,
                              hipStream_t stream)
{
    const void* x  = d_in[0];
    const void* nu = d_in[1];
    const void* th = d_in[2];
    const void* Br = d_in[3];
    const void* Bi = d_in[4];
    const void* Cr = d_in[5];
    const void* Ci = d_in[6];
    const void* D  = d_in[7];

    char* ws = (char*)d_ws;
    float* lam    = (float*)(ws);
    float* lam64  = (float*)(ws + 512);
    int*   flags  = (int*)(ws + 1024);
    float* Df     = (float*)(ws + 1088);
    float* CBt    = (float*)(ws + 2112);
    float* Ktab   = (float*)(ws + 133184);
    short* VreT   = (short*)(ws + 198720);
    short* VimnT  = (short*)(ws + 206912);
    float* PsegRe = (float*)(ws + 215104);
    float* PsegIm = (float*)(ws + 231744);
    short* PreH   = (short*)(ws + 248128);
    short* PreL   = (short*)(ws + 256320);
    short* PimH   = (short*)(ws + 264512);
    short* PimL   = (short*)(ws + 272704);
    unsigned int* Apack = (unsigned int*)(ws + 294912);
    float* yout = (float*)d_out;

    k_setup<<<dim3(64), dim3(256), 0, stream>>>(x, nu, th, Br, Bi, Cr, Ci, D,
                                                flags, lam, lam64, Df, CBt,
                                                PsegRe, PsegIm);
    k_ktab<<<dim3(64), dim3(256), 0, stream>>>(CBt, PsegRe, PsegIm, lam64,
                                               Ktab, VreT, VimnT,
                                               PreH, PreL, PimH, PimL);
    k_segsum<<<dim3(512), dim3(256), 0, stream>>>(x, PreH, PreL, PimH, PimL,
                                                  flags, Apack);
    k_scan<<<dim3(256), dim3(256), 0, stream>>>(lam64, CBt, Apack);
    k_cc<<<dim3(512), dim3(1024), 0, stream>>>(VreT, VimnT, Apack,
                                               x, Df, Ktab, flags, yout);
}